// Round 5
// baseline (560.473 us; speedup 1.0000x reference)
//
#include <hip/hip_runtime.h>
#include <stdint.h>
#include <stddef.h>

#define NN 100000
#define NE 1600000
#define DD 32
#define NCAND 1024
#define HSIZE 65536
#define SORTN 4096
#define SCAN_B 1024
#define NB ((NN + SCAN_B - 1) / SCAN_B)   // 98 scan blocks
#define NTB 128                            // build3 block size
#define KCAP 48                            // padded slots/row (Poisson(16): P(d>48)~1e-11/row)
#define OVFCAP 1024
#define COLM 0x1FFFF                       // col mask (col<2^17); lv in bits 17..18

// ---------------- JAX threefry2x32 (20 rounds) ----------------
__host__ __device__ inline void tf2x32(uint32_t k0, uint32_t k1, uint32_t x0, uint32_t x1,
                                       uint32_t& o0, uint32_t& o1) {
  uint32_t ks2 = k0 ^ k1 ^ 0x1BD11BDAu;
  uint32_t v0 = x0 + k0, v1 = x1 + k1;
#define TFR(r) { v0 += v1; v1 = (v1 << (r)) | (v1 >> (32 - (r))); v1 ^= v0; }
  TFR(13) TFR(15) TFR(26) TFR(6)   v0 += k1;  v1 += ks2 + 1u;
  TFR(17) TFR(29) TFR(16) TFR(24)  v0 += ks2; v1 += k0 + 2u;
  TFR(13) TFR(15) TFR(26) TFR(6)   v0 += k0;  v1 += k1 + 3u;
  TFR(17) TFR(29) TFR(16) TFR(24)  v0 += k1;  v1 += ks2 + 4u;
  TFR(13) TFR(15) TFR(26) TFR(6)   v0 += ks2; v1 += k0 + 5u;
#undef TFR
  o0 = v0; o1 = v1;
}

__device__ __forceinline__ uint32_t jax_bits32(uint32_t k0, uint32_t k1, uint32_t i) {
  uint32_t o0, o1;
  tf2x32(k0, k1, 0u, i, o0, o1);
  return o0 ^ o1;
}

__device__ __forceinline__ float bits_to_uniform(uint32_t b) {
  return __fsub_rn(__uint_as_float((b >> 9) | 0x3f800000u), 1.0f);
}

// numpy-pairwise sum of 32 floats
__device__ __forceinline__ float pairwise32(const float* x) {
  float r[8];
#pragma unroll
  for (int j = 0; j < 8; ++j) r[j] = x[j];
#pragma unroll
  for (int b = 8; b < 32; b += 8)
#pragma unroll
    for (int j = 0; j < 8; ++j) r[j] = __fadd_rn(r[j], x[b + j]);
  float a01 = __fadd_rn(r[0], r[1]), a23 = __fadd_rn(r[2], r[3]);
  float a45 = __fadd_rn(r[4], r[5]), a67 = __fadd_rn(r[6], r[7]);
  return __fadd_rn(__fadd_rn(a01, a23), __fadd_rn(a45, a67));
}

// ---------------- kernels ----------------

// fused: threefry levels + per-row count (u32 atomic, returned old = seq) +
// scattered 16B payload into padded row-major layout. One edge pass total.
__global__ void k_fused(const int* __restrict__ rows, const int* __restrict__ cols,
                        const float* __restrict__ adj,
                        uint32_t k00, uint32_t k01, uint32_t k10, uint32_t k11,
                        uint32_t k20, uint32_t k21,
                        uint32_t* __restrict__ cnt32, int4* __restrict__ pkPad,
                        int4* __restrict__ ovfBuf, int* __restrict__ ovfCnt) {
  int e = blockIdx.x * blockDim.x + threadIdx.x;
  if (e >= NE) return;
  float u0 = bits_to_uniform(jax_bits32(k00, k01, (uint32_t)e));
  float u1 = bits_to_uniform(jax_bits32(k10, k11, (uint32_t)e));
  float u2 = bits_to_uniform(jax_bits32(k20, k21, (uint32_t)e));
  float kp0 = floorf(__fadd_rn(u0, 0.5f));
  float kp1 = floorf(__fadd_rn(u1, 0.25f));
  float kp2 = floorf(__fadd_rn(u2, 0.125f));
  int lv = 0;
  if (kp0 != 0.0f) { lv = 1; if (kp1 != 0.0f) { lv = 2; if (kp2 != 0.0f) lv = 3; } }
  int c = cols[e];
  int ab = __float_as_int(adj[e]);
  int r = rows[e];
  uint32_t seq = atomicAdd(&cnt32[r], 1u);
  int4 pl = make_int4((lv << 17) | c, ab, e, r);
  if (seq < KCAP) {
    pkPad[(size_t)r * KCAP + seq] = pl;
  } else {
    int q = atomicAdd(ovfCnt, 1);
    if (q < OVFCAP) ovfBuf[q] = pl;
  }
}

// single-array exclusive scan of cnt32 -> rp
__global__ void k_scan1(const uint32_t* __restrict__ cnt32, int* __restrict__ rp,
                        int* __restrict__ bsum) {
  __shared__ int s[SCAN_B];
  int gid = blockIdx.x * SCAN_B + threadIdx.x;
  int v = (gid < NN) ? (int)cnt32[gid] : 0;
  s[threadIdx.x] = v;
  __syncthreads();
  for (int off = 1; off < SCAN_B; off <<= 1) {
    int t = (threadIdx.x >= off) ? s[threadIdx.x - off] : 0;
    __syncthreads();
    s[threadIdx.x] += t;
    __syncthreads();
  }
  if (gid < NN) rp[gid] = s[threadIdx.x] - v;  // exclusive
  if (threadIdx.x == SCAN_B - 1) bsum[blockIdx.x] = s[threadIdx.x];
}

__global__ void k_scan2(int* __restrict__ bsum) {
  __shared__ int s[128];
  int t = threadIdx.x;
  int v = (t < NB) ? bsum[t] : 0;
  s[t] = v;
  __syncthreads();
  for (int off = 1; off < 128; off <<= 1) {
    int x = (t >= off) ? s[t - off] : 0;
    __syncthreads();
    s[t] += x;
    __syncthreads();
  }
  if (t < NB) bsum[t] = s[t] - v;  // exclusive
}

__global__ void k_scan3(int* __restrict__ rp, const int* __restrict__ bsum,
                        const uint32_t* __restrict__ cnt32) {
  int gid = blockIdx.x * SCAN_B + threadIdx.x;
  if (gid < NN) {
    int v = rp[gid] + bsum[gid / SCAN_B];
    rp[gid] = v;
    if (gid == NN - 1) rp[NN] = v + (int)cnt32[gid];
  }
}

// per-row: LDS sort padded entries by eid, emit single compact list (lv packed in x),
// compute order0/1/2 in sorted (reference) accumulation order
__global__ __launch_bounds__(NTB) void k_build3(
    const uint32_t* __restrict__ cnt32, const int* __restrict__ rp,
    const int4* __restrict__ pkPad, const int4* __restrict__ ovfBuf,
    const int* __restrict__ ovfCnt, int2* __restrict__ pk,
    float* __restrict__ order0, float* __restrict__ order1, float* __restrict__ order2) {
  __shared__ uint32_t K[KCAP * NTB];  // transposed: K[i*NTB+t]
  int t = threadIdx.x;
  int r = blockIdx.x * NTB + t;
  if (r >= NN) return;  // no __syncthreads below; LDS column is thread-private
  int d = (int)cnt32[r];
  int base = rp[r];
  float o0 = 0.0f, o1 = 0.0f, o2 = 0.0f;
  if (d <= KCAP) {
    const int4* src = pkPad + (size_t)r * KCAP;
    for (int i = 0; i < d; ++i)
      K[i * NTB + t] = ((uint32_t)src[i].z << 6) | (uint32_t)i;  // eid<2^21, i<48
    for (int i = 1; i < d; ++i) {
      uint32_t key = K[i * NTB + t];
      int j = i - 1;
      while (j >= 0) {
        uint32_t kj = K[j * NTB + t];
        if (kj <= key) break;
        K[(j + 1) * NTB + t] = kj;
        --j;
      }
      K[(j + 1) * NTB + t] = key;
    }
    for (int i = 0; i < d; ++i) {
      int idx = (int)(K[i * NTB + t] & 63u);
      int4 p = src[idx];  // L1-hot re-read
      float a = __int_as_float(p.y);
      int lv = p.x >> 17;
      o0 = __fadd_rn(o0, a);
      if (lv >= 1) {
        o1 = __fadd_rn(o1, a);
        if (lv >= 2) o2 = __fadd_rn(o2, a);
      }
      pk[base + i] = make_int2(p.x, p.y);
    }
  } else {
    // effectively-never overflow path (d>KCAP): merge padded + overflow capture
    int4 tmp[96];
    int dd = 0;
    for (int i = 0; i < KCAP; ++i) tmp[dd++] = pkPad[(size_t)r * KCAP + i];
    int n = *ovfCnt; if (n > OVFCAP) n = OVFCAP;
    for (int q = 0; q < n; ++q) {
      int4 p = ovfBuf[q];
      if (p.w == r && dd < 96) tmp[dd++] = p;
    }
    for (int i = 1; i < dd; ++i) {
      int4 key = tmp[i];
      int j = i - 1;
      while (j >= 0 && tmp[j].z > key.z) { tmp[j + 1] = tmp[j]; --j; }
      tmp[j + 1] = key;
    }
    for (int i = 0; i < dd; ++i) {
      int4 p = tmp[i];
      float a = __int_as_float(p.y);
      int lv = p.x >> 17;
      o0 = __fadd_rn(o0, a);
      if (lv >= 1) {
        o1 = __fadd_rn(o1, a);
        if (lv >= 2) o2 = __fadd_rn(o2, a);
      }
      pk[base + i] = make_int2(p.x, p.y);
    }
  }
  order0[r] = o0; order1[r] = o1; order2[r] = o2;
}

// fst_emb = spmm(adj, embeds) - embeds
__global__ void k_emb0(const int* __restrict__ rp, const int2* __restrict__ pk,
                       const float* __restrict__ embeds, float* __restrict__ e0) {
  int tid = blockIdx.x * blockDim.x + threadIdx.x;
  int r = tid >> 5, d = tid & 31;
  if (r >= NN) return;
  int s = rp[r], t = rp[r + 1];
  float acc = 0.0f;
  for (int base = s; base < t; base += 32) {
    int idx = base + d;
    int2 p = (idx < t) ? pk[idx] : make_int2(0, 0);
    int m = t - base; if (m > 32) m = 32;
    for (int j = 0; j < m; ++j) {
      int cv = __shfl(p.x, j, 32);
      int ab = __shfl(p.y, j, 32);
      float x = embeds[(size_t)(cv & COLM) * DD + d];
      acc = __fadd_rn(acc, __fmul_rn(__int_as_float(ab), x));
    }
  }
  e0[(size_t)r * DD + d] = __fsub_rn(acc, embeds[(size_t)r * DD + d]);
}

// emb_next = spmm(stage vals, emb_cur) - emb_cur - order*emb_cur; lv filter inline
// mode: 1 = S = ec + o (init), write next; 2 = S += o, write next; 3 = S += o only
__global__ void k_emb_step(const int* __restrict__ rp, const int2* __restrict__ pk,
                           const float* __restrict__ ord, const float* __restrict__ ecur,
                           float* __restrict__ enext, float* __restrict__ esum,
                           int stage, int mode) {
  int tid = blockIdx.x * blockDim.x + threadIdx.x;
  int r = tid >> 5, d = tid & 31;
  if (r >= NN) return;
  int s = rp[r], t = rp[r + 1];
  float acc = 0.0f;
  for (int base = s; base < t; base += 32) {
    int idx = base + d;
    int2 p = (idx < t) ? pk[idx] : make_int2(0, 0);
    int m = t - base; if (m > 32) m = 32;
    for (int j = 0; j < m; ++j) {
      int cv = __shfl(p.x, j, 32);
      if ((cv >> 17) >= stage) {  // wave-uniform branch
        int ab = __shfl(p.y, j, 32);
        float x = ecur[(size_t)(cv & COLM) * DD + d];
        acc = __fadd_rn(acc, __fmul_rn(__int_as_float(ab), x));
      }
    }
  }
  size_t idx = (size_t)r * DD + d;
  float ec = ecur[idx];
  float o = __fsub_rn(__fsub_rn(acc, ec), __fmul_rn(ord[r], ec));
  if (mode != 3) enext[idx] = o;
  if (mode == 1) esum[idx] = __fadd_rn(ec, o);
  else esum[idx] = __fadd_rn(esum[idx], o);
}

// num_next = spmm(stage vals, num_cur) - num_cur - order; lv filter inline
__global__ void k_num_step(const int* __restrict__ rp, const int2* __restrict__ pk,
                           const float* __restrict__ ord, const float* __restrict__ ncur,
                           float* __restrict__ nnext, float* __restrict__ nsum,
                           int stage, int mode) {
  int r = blockIdx.x * blockDim.x + threadIdx.x;
  if (r >= NN) return;
  int s = rp[r], t = rp[r + 1];
  float acc = 0.0f;
  for (int k = s; k < t; ++k) {
    int2 p = pk[k];
    if ((p.x >> 17) >= stage)
      acc = __fadd_rn(acc, __fmul_rn(__int_as_float(p.y), ncur[p.x & COLM]));
  }
  float nc = ncur[r];
  float o = __fsub_rn(__fsub_rn(acc, nc), ord[r]);
  if (mode != 3) nnext[r] = o;
  if (mode == 1) nsum[r] = __fadd_rn(nc, o);
  else nsum[r] = __fadd_rn(nsum[r], o);
}

__global__ void k_final(const float* __restrict__ embeds, const float* __restrict__ emb_sum,
                        const float* __restrict__ num_sum, uint32_t gk0, uint32_t gk1,
                        float* __restrict__ out_scores, int* __restrict__ hist) {
  int r = blockIdx.x * blockDim.x + threadIdx.x;
  if (r >= NN) return;
  float denom = __fadd_rn(num_sum[r], 1e-8f);
  float sub[DD], em[DD], pr[DD];
  const float4* ps = (const float4*)(emb_sum + (size_t)r * DD);
  const float4* pe = (const float4*)(embeds + (size_t)r * DD);
#pragma unroll
  for (int j = 0; j < 8; ++j) {
    float4 a = ps[j], b = pe[j];
    sub[4 * j + 0] = __fdiv_rn(a.x, denom); sub[4 * j + 1] = __fdiv_rn(a.y, denom);
    sub[4 * j + 2] = __fdiv_rn(a.z, denom); sub[4 * j + 3] = __fdiv_rn(a.w, denom);
    em[4 * j + 0] = b.x; em[4 * j + 1] = b.y; em[4 * j + 2] = b.z; em[4 * j + 3] = b.w;
  }
#pragma unroll
  for (int d = 0; d < DD; ++d) pr[d] = __fmul_rn(sub[d], sub[d]);
  float n1 = fmaxf(__fsqrt_rn(pairwise32(pr)), 1e-12f);
#pragma unroll
  for (int d = 0; d < DD; ++d) pr[d] = __fmul_rn(em[d], em[d]);
  float n2 = fmaxf(__fsqrt_rn(pairwise32(pr)), 1e-12f);
#pragma unroll
  for (int d = 0; d < DD; ++d)
    pr[d] = __fmul_rn(__fdiv_rn(sub[d], n1), __fdiv_rn(em[d], n2));
  float dot = pairwise32(pr);
  float u = bits_to_uniform(jax_bits32(gk0, gk1, (uint32_t)r));
  float l1 = (float)log((double)u);
  float w = -l1;
  float l2 = (float)log((double)w);
  float g = -l2;
  float score = __fadd_rn(dot, g);
  out_scores[r] = score;
  uint32_t kb = __float_as_uint(score);
  kb = (kb & 0x80000000u) ? ~kb : (kb | 0x80000000u);
  atomicAdd(&hist[kb >> 16], 1);
}

__global__ void k_cutoff(const int* __restrict__ hist, int* __restrict__ cutoff) {
  __shared__ int psum[1024];
  int t = threadIdx.x;
  int base = HSIZE - (t + 1) * 64;
  int own = 0;
  for (int i = 0; i < 64; ++i) own += hist[base + i];
  psum[t] = own;
  __syncthreads();
  for (int off = 1; off < 1024; off <<= 1) {
    int v = (t >= off) ? psum[t - off] : 0;
    __syncthreads();
    psum[t] += v;
    __syncthreads();
  }
  int incl = psum[t];
  int prev = incl - own;
  if (incl >= NCAND && prev < NCAND) {
    int c = prev;
    int b = HSIZE - t * 64 - 1;
    while (b >= base) {
      c += hist[b];
      if (c >= NCAND) break;
      --b;
    }
    *cutoff = b;
  }
}

__global__ void k_collect(const float* __restrict__ scores, const int* __restrict__ cutoff,
                          unsigned long long* __restrict__ buf, int* __restrict__ cnt2) {
  int r = blockIdx.x * blockDim.x + threadIdx.x;
  if (r >= NN) return;
  uint32_t kb = __float_as_uint(scores[r]);
  kb = (kb & 0x80000000u) ? ~kb : (kb | 0x80000000u);
  if ((int)(kb >> 16) >= *cutoff) {
    int p = atomicAdd(cnt2, 1);
    if (p < SORTN)
      buf[p] = ((unsigned long long)kb << 32) | (uint32_t)(~(uint32_t)r);
  }
}

__global__ __launch_bounds__(1024) void k_sort(const unsigned long long* __restrict__ buf,
                                               const int* __restrict__ cnt2,
                                               float* __restrict__ out_cand) {
  __shared__ unsigned long long s[SORTN];
  int m = *cnt2;
  if (m > SORTN) m = SORTN;
  for (int i = threadIdx.x; i < SORTN; i += 1024) s[i] = (i < m) ? buf[i] : 0ull;
  __syncthreads();
  for (int k = 2; k <= SORTN; k <<= 1) {
    for (int j = k >> 1; j > 0; j >>= 1) {
      for (int i = threadIdx.x; i < SORTN; i += 1024) {
        int ixj = i ^ j;
        if (ixj > i) {
          unsigned long long a = s[i], b = s[ixj];
          bool desc = ((i & k) == 0);
          if (desc ? (a < b) : (a > b)) { s[i] = b; s[ixj] = a; }
        }
      }
      __syncthreads();
    }
  }
  for (int i = threadIdx.x; i < NCAND; i += 1024) {
    uint32_t idx = ~((uint32_t)(s[i] & 0xffffffffull));
    out_cand[i] = (float)idx;
  }
}

// ---------------- host ----------------
extern "C" void kernel_launch(void* const* d_in, const int* in_sizes, int n_in,
                              void* d_out, int out_size, void* d_ws, size_t ws_size,
                              hipStream_t stream) {
  const int* rows = (const int*)d_in[0];
  const int* cols = rows + NE;
  const float* adj = (const float*)d_in[1];
  const float* embeds = (const float*)d_in[2];
  float* out = (float*)d_out;

  char* p = (char*)d_ws;
  auto alloc = [&](size_t bytes) {
    char* q = p;
    p += (bytes + 255) & ~(size_t)255;
    return q;
  };
  // single contiguous zero region: cnt32 | hist | cnt2(2) | ovfCnt(1)
  size_t zero_bytes = (size_t)NN * 4 + (size_t)HSIZE * 4 + 256;
  char* zero_base = (char*)alloc(zero_bytes);
  uint32_t* cnt32 = (uint32_t*)zero_base;
  int* hist = (int*)(cnt32 + NN);
  int* cnt2 = hist + HSIZE;   // [0]=collect count, [1]=cutoff bin
  int* ovfCnt = cnt2 + 2;

  int* rp = (int*)alloc((NN + 1) * 4);
  int* bsum = (int*)alloc(128 * 4);
  // pkPad (76.8 MB) is dead after k_build3; embA/embB/embS overlay it.
  char* padBase = (char*)alloc((size_t)NN * KCAP * 16);
  int4* pkPad = (int4*)padBase;
  float* embA = (float*)padBase;                            // 12.8 MB
  float* embB = (float*)(padBase + (size_t)NN * DD * 4);    // 12.8 MB
  float* embS = (float*)(padBase + (size_t)2 * NN * DD * 4);// 12.8 MB
  int2* pk = (int2*)alloc((size_t)NE * 8);
  int4* ovfBuf = (int4*)alloc((size_t)OVFCAP * 16);
  float* order0 = (float*)alloc(NN * 4);
  float* order1 = (float*)alloc(NN * 4);
  float* order2 = (float*)alloc(NN * 4);
  float* num1 = (float*)alloc(NN * 4);
  float* num2 = (float*)alloc(NN * 4);
  float* numS = (float*)alloc(NN * 4);
  unsigned long long* buf = (unsigned long long*)alloc(SORTN * 8);

  uint32_t dk[3][2];
  for (int i = 0; i < 3; ++i) tf2x32(0u, 42u, 0u, (uint32_t)i, dk[i][0], dk[i][1]);

  hipMemsetAsync(zero_base, 0, zero_bytes, stream);

  k_fused<<<(NE + 255) / 256, 256, 0, stream>>>(
      rows, cols, adj, dk[0][0], dk[0][1], dk[1][0], dk[1][1], dk[2][0], dk[2][1],
      cnt32, pkPad, ovfBuf, ovfCnt);

  k_scan1<<<NB, SCAN_B, 0, stream>>>(cnt32, rp, bsum);
  k_scan2<<<1, 128, 0, stream>>>(bsum);
  k_scan3<<<NB, SCAN_B, 0, stream>>>(rp, bsum, cnt32);

  k_build3<<<(NN + NTB - 1) / NTB, NTB, 0, stream>>>(cnt32, rp, pkPad, ovfBuf, ovfCnt,
                                                     pk, order0, order1, order2);

  int gEmb = (NN * 32 + 255) / 256;
  k_emb0<<<gEmb, 256, 0, stream>>>(rp, pk, embeds, embA);

  // stage 1: cur=embA -> next=embB, S init
  k_emb_step<<<gEmb, 256, 0, stream>>>(rp, pk, order0, embA, embB, embS, 1, 1);
  k_num_step<<<(NN + 255) / 256, 256, 0, stream>>>(rp, pk, order0, order0, num1, numS, 1, 1);
  // stage 2: cur=embB -> next=embA, S +=
  k_emb_step<<<gEmb, 256, 0, stream>>>(rp, pk, order1, embB, embA, embS, 2, 2);
  k_num_step<<<(NN + 255) / 256, 256, 0, stream>>>(rp, pk, order1, num1, num2, numS, 2, 2);
  // stage 3: cur=embA, S += only
  k_emb_step<<<gEmb, 256, 0, stream>>>(rp, pk, order2, embA, (float*)nullptr, embS, 3, 3);
  k_num_step<<<(NN + 255) / 256, 256, 0, stream>>>(rp, pk, order2, num2, (float*)nullptr,
                                                   numS, 3, 3);

  k_final<<<(NN + 255) / 256, 256, 0, stream>>>(embeds, embS, numS, 0u, 7u, out, hist);
  k_cutoff<<<1, 1024, 0, stream>>>(hist, cnt2 + 1);
  k_collect<<<(NN + 255) / 256, 256, 0, stream>>>(out, cnt2 + 1, buf, cnt2);
  k_sort<<<1, 1024, 0, stream>>>(buf, cnt2, out + NN);
}